// Round 22
// baseline (358.423 us; speedup 1.0000x reference)
//
#include <hip/hip_runtime.h>
#include <hip/hip_bf16.h>
#include <math.h>

#define T_STEPS 2048
#define B_SZ 16
#define D_SZ 1024
#define N_SZ 64
#define M_ROWS (T_STEPS * B_SZ)   // 32768
#define NOUT (4 * N_SZ)           // 256
#define U_BLK 8
#define NBLK (T_STEPS / U_BLK)    // 256
#define TSTR 17                   // transposed kn/q LDS row stride (floats)

typedef __attribute__((ext_vector_type(8))) short bf16x8;
typedef __attribute__((ext_vector_type(4))) float f32x4;

// ---------------------------------------------------------------------------
// DPP reductions.
// ---------------------------------------------------------------------------
template <int CTRL, int RMASK, bool BC>
__device__ __forceinline__ float dpp_add(float v) {
  return v + __int_as_float(__builtin_amdgcn_update_dpp(
                 0, __float_as_int(v), CTRL, RMASK, 0xF, BC));
}
// full 64-lane reduce, uniform result (gram kernel)
__device__ __forceinline__ float wave_red(float v) {
  v = dpp_add<0xB1, 0xF, true>(v);
  v = dpp_add<0x4E, 0xF, true>(v);
  v = dpp_add<0x141, 0xF, true>(v);
  v = dpp_add<0x140, 0xF, true>(v);
  v = dpp_add<0x142, 0xA, false>(v);
  v = dpp_add<0x143, 0xC, false>(v);
  return __int_as_float(__builtin_amdgcn_readlane(__float_as_int(v), 63));
}
// 16-lane reduce: uniform within each 16-lane row (GEMM epilogue k-norm)
__device__ __forceinline__ float red16(float v) {
  v = dpp_add<0xB1, 0xF, true>(v);    // xor 1
  v = dpp_add<0x4E, 0xF, true>(v);    // xor 2
  v = dpp_add<0x141, 0xF, true>(v);   // xor 4
  v = dpp_add<0x140, 0xF, true>(v);   // xor 8
  return v;
}

// fp32 pair -> packed bf16x2 (RNE) via v_cvt_pk_bf16_f32.
__device__ __forceinline__ unsigned cvt2(float a, float b) {
  float2 f; f.x = a; f.y = b;
  __hip_bfloat162 h = __float22bfloat162_rn(f);
  return *reinterpret_cast<unsigned*>(&h);
}

// ---------------------------------------------------------------------------
// Kernel 0: W (fp32, 1 MB) -> Wb (bf16, 0.5 MB), once (R20-verified).
// ---------------------------------------------------------------------------
__global__ __launch_bounds__(256) void wcvt(const float* __restrict__ W,
                                            unsigned* __restrict__ Wb) {
  const size_t idx = ((size_t)blockIdx.x * 256 + threadIdx.x) * 4;
  const float4 f = *reinterpret_cast<const float4*>(&W[idx]);
  uint2 o;
  o.x = cvt2(f.x, f.y);
  o.y = cvt2(f.z, f.w);
  *reinterpret_cast<uint2*>(&Wb[idx >> 1]) = o;
}

// ---------------------------------------------------------------------------
// Kernel 1: proj = x @ W^T via bf16 MFMA (R20 structure) with FUSED
// norm/gate/repack epilogue.  The block's 64x256 tile has wave0=k, wave1=v,
// wave2=q, wave3=g.  Epilogue: wave0 16-lane-DPP k-norm -> kn to LDS;
// wave3 sigmoid(g+bg) -> dec to LDS (both overlaid on dead Al/Bl); barrier;
// wave2 writes (kn,q) pairs, wave1 writes (v,dec) pairs -> repacked proj.
// ---------------------------------------------------------------------------
__global__ __launch_bounds__(256) void gemm_proj(
    const float* __restrict__ x, const unsigned short* __restrict__ Wb,
    float* __restrict__ proj, const float* __restrict__ b_gate) {
  __shared__ char smem[46080];
  auto Al = (unsigned short (*)[72])smem;                 // 64x72x2 = 9216
  auto Bl = (unsigned short (*)[72])(smem + 9216);        // 256x72x2 = 36864
  auto knb = (float (*)[68])smem;                         // 64x68x4 = 17408
  auto decb = (float (*)[68])(smem + 17408);              // +17408 <= 46080

  const int tid = threadIdx.x;
  const int lane = tid & 63;
  const int wv = tid >> 6;
  const int m0 = blockIdx.x * 64;
  const int nw0 = wv * 64;

  f32x4 acc[4][4];
#pragma unroll
  for (int m = 0; m < 4; ++m)
#pragma unroll
    for (int n = 0; n < 4; ++n) acc[m][n] = (f32x4){0.f, 0.f, 0.f, 0.f};

  const int arow = tid >> 2;
  const int akb = (tid & 3) * 16;

  for (int k0 = 0; k0 < D_SZ; k0 += 64) {
    {
      const float* src = &x[(size_t)(m0 + arow) * D_SZ + k0 + akb];
      unsigned tmp[8];
#pragma unroll
      for (int c = 0; c < 4; ++c) {
        const float4 f = *reinterpret_cast<const float4*>(src + c * 4);
        tmp[2 * c] = cvt2(f.x, f.y);
        tmp[2 * c + 1] = cvt2(f.z, f.w);
      }
      *reinterpret_cast<float4*>(&Al[arow][akb]) =
          *reinterpret_cast<const float4*>(&tmp[0]);
      *reinterpret_cast<float4*>(&Al[arow][akb + 8]) =
          *reinterpret_cast<const float4*>(&tmp[4]);
    }
    {
      const unsigned short* src = &Wb[(size_t)tid * D_SZ + k0];
#pragma unroll
      for (int h = 0; h < 8; ++h)
        *reinterpret_cast<float4*>(&Bl[tid][h * 8]) =
            *reinterpret_cast<const float4*>(&src[h * 8]);
    }
    __syncthreads();
    const int fr = lane & 15;
#pragma unroll
    for (int kk = 0; kk < 64; kk += 32) {
      const int kof = kk + (lane >> 4) * 8;
      bf16x8 af[4], bfr[4];
#pragma unroll
      for (int m = 0; m < 4; ++m)
        af[m] = *reinterpret_cast<const bf16x8*>(&Al[m * 16 + fr][kof]);
#pragma unroll
      for (int n = 0; n < 4; ++n)
        bfr[n] = *reinterpret_cast<const bf16x8*>(&Bl[nw0 + n * 16 + fr][kof]);
#pragma unroll
      for (int m = 0; m < 4; ++m)
#pragma unroll
        for (int n = 0; n < 4; ++n)
          acc[m][n] = __builtin_amdgcn_mfma_f32_16x16x32_bf16(
              af[m], bfr[n], acc[m][n], 0, 0, 0);
    }
    __syncthreads();
  }

  // ---- fused epilogue ----
  const int l15 = lane & 15;
  const int lg = lane >> 4;
  if (wv == 0) {
#pragma unroll
    for (int m = 0; m < 4; ++m)
#pragma unroll
      for (int r = 0; r < 4; ++r) {
        float part = 0.f;
#pragma unroll
        for (int n = 0; n < 4; ++n)
          part = fmaf(acc[m][n][r], acc[m][n][r], part);
        const float ss = red16(part);
        const float rk = 1.f / (sqrtf(ss) + 1e-6f);
        const int row = m * 16 + lg * 4 + r;
#pragma unroll
        for (int n = 0; n < 4; ++n)
          knb[row][n * 16 + l15] = acc[m][n][r] * rk;
      }
  } else if (wv == 3) {
#pragma unroll
    for (int m = 0; m < 4; ++m)
#pragma unroll
      for (int r = 0; r < 4; ++r) {
        const int row = m * 16 + lg * 4 + r;
#pragma unroll
        for (int n = 0; n < 4; ++n) {
          const float g = acc[m][n][r];
          decb[row][n * 16 + l15] =
              1.f / (1.f + expf(-(g + b_gate[n * 16 + l15])));
        }
      }
  }
  __syncthreads();
  if (wv == 2) {           // (kn, q) pairs -> proj cols [0,128)
#pragma unroll
    for (int m = 0; m < 4; ++m)
#pragma unroll
      for (int r = 0; r < 4; ++r) {
        const int row = m * 16 + lg * 4 + r;
#pragma unroll
        for (int n = 0; n < 4; ++n) {
          const int qc = n * 16 + l15;
          float2 pr; pr.x = knb[row][qc]; pr.y = acc[m][n][r];
          *reinterpret_cast<float2*>(
              &proj[(size_t)(m0 + row) * NOUT + qc * 2]) = pr;
        }
      }
  } else if (wv == 1) {    // (v, dec) pairs -> proj cols [128,256)
#pragma unroll
    for (int m = 0; m < 4; ++m)
#pragma unroll
      for (int r = 0; r < 4; ++r) {
        const int row = m * 16 + lg * 4 + r;
#pragma unroll
        for (int n = 0; n < 4; ++n) {
          const int vc = n * 16 + l15;
          float2 pr; pr.x = acc[m][n][r]; pr.y = decb[row][vc];
          *reinterpret_cast<float2*>(
              &proj[(size_t)(m0 + row) * NOUT + 128 + vc * 2]) = pr;
        }
      }
  }
}

// ---------------------------------------------------------------------------
// Kernel 2: Gram precompute (R13-verified body; reads repacked (kn,q) pairs).
// ---------------------------------------------------------------------------
__global__ __launch_bounds__(256) void gram_kernel(const float* __restrict__ proj,
                                                   float* __restrict__ gram) {
  const int wid = threadIdx.x >> 6;
  const int lane = threadIdx.x & 63;
  const int gw = blockIdx.x * 4 + wid;
  const int a = gw & 7;
  const int grp = gw >> 3;                  // b*NBLK + blk
  const int blk = grp & (NBLK - 1);
  const int b = grp >> 8;
  const int t0 = blk * U_BLK;
  const float2* base = reinterpret_cast<const float2*>(proj);

  float2 knq[8];
#pragma unroll
  for (int c = 0; c < 8; ++c)
    knq[c] = base[(size_t)((t0 + c) * B_SZ + b) * 128 + lane];
  const float2 mine = knq[a];

  float row[8];
#pragma unroll
  for (int c = 0; c < 8; ++c) {
    const float lhs = (c > a) ? mine.x : mine.y;
    row[c] = wave_red(lhs * knq[c].x);
  }
  if (lane == 0) {
    float* dst = gram + ((size_t)grp * 64 + a * 8);
    float4 r0, r1;
    r0.x = row[0]; r0.y = row[1]; r0.z = row[2]; r0.w = row[3];
    r1.x = row[4]; r1.y = row[5]; r1.z = row[6]; r1.w = row[7];
    *reinterpret_cast<float4*>(dst) = r0;
    *reinterpret_cast<float4*>(dst + 4) = r1;
  }
}

// ---------------------------------------------------------------------------
// Kernel 3: scan — R18 structure with silu FUSED into the output write:
// sqv[] is wave-uniform; 7-cndmask static tree gives lane u sqv[u]; lanes
// 0..7 compute sq^2*sigmoid(sq) and store in parallel.  Rest byte-identical.
// ---------------------------------------------------------------------------
__global__ __launch_bounds__(256, 1) void scan_kernel(
    const float* __restrict__ proj, const float* __restrict__ gram,
    const float* __restrict__ S0, float* __restrict__ out,
    float* __restrict__ Sfin) {
  const int wid = threadIdx.x >> 6;     // 0..3
  const int lane = threadIdx.x & 63;
  const int bid = blockIdx.x;
  const int b = (bid & 7) | ((bid >> 7) << 3);     // same XCD for same b
  const int i = (((bid >> 3) & 15) << 2) | wid;

  __shared__ float ldsT[2][64 * TSTR];   // transposed kn/q: [j][u | 8+u]
  __shared__ float ldsV[2][U_BLK * 128]; // row-major (v,dec) pairs
  __shared__ float ldsG[2][64];          // gram row
  __shared__ float ldsS[4][64];          // per-wave S scratch

  float S = S0[(size_t)b * 4096 + i * 64 + lane];

  const int r0 = wid * 2;           // this wave stages rows r0, r0+1
  float4 st0, st1;
  float stg = 0.f;

#define STAGE_LOAD(blkv)                                                      \
  {                                                                           \
    const size_t g0 = ((size_t)(((blkv) * U_BLK + r0) * B_SZ + b)) * NOUT;    \
    st0 = *reinterpret_cast<const float4*>(&proj[g0 + lane * 4]);             \
    st1 = *reinterpret_cast<const float4*>(&proj[g0 + (size_t)B_SZ * NOUT +   \
                                                 lane * 4]);                  \
    if (wid == 0) stg = gram[((size_t)b * NBLK + (blkv)) * 64 + lane];        \
  }

#define STAGE_WRITE(bufv)                                                     \
  {                                                                           \
    if (lane < 32) {                                                          \
      const int j0 = lane * 2;                                                \
      ldsT[bufv][j0 * TSTR + r0] = st0.x;                                     \
      ldsT[bufv][j0 * TSTR + 8 + r0] = st0.y;                                 \
      ldsT[bufv][(j0 + 1) * TSTR + r0] = st0.z;                               \
      ldsT[bufv][(j0 + 1) * TSTR + 8 + r0] = st0.w;                           \
      ldsT[bufv][j0 * TSTR + r0 + 1] = st1.x;                                 \
      ldsT[bufv][j0 * TSTR + 8 + r0 + 1] = st1.y;                             \
      ldsT[bufv][(j0 + 1) * TSTR + r0 + 1] = st1.z;                           \
      ldsT[bufv][(j0 + 1) * TSTR + 8 + r0 + 1] = st1.w;                       \
    } else {                                                                  \
      *reinterpret_cast<float4*>(                                             \
          &ldsV[bufv][r0 * 128 + (lane - 32) * 4]) = st0;                     \
      *reinterpret_cast<float4*>(                                             \
          &ldsV[bufv][(r0 + 1) * 128 + (lane - 32) * 4]) = st1;               \
    }                                                                         \
    if (wid == 0) ldsG[bufv][lane] = stg;                                     \
  }

#define GM(idx) __int_as_float(                                               \
    __builtin_amdgcn_readlane(__float_as_int(gv), (idx)))

  STAGE_LOAD(0)
  STAGE_WRITE(0)
  __syncthreads();

  const int koff = (lane >> 4) * 8;
  const int col = lane & 15;

  for (int blk = 0; blk < NBLK; ++blk) {
    const int buf = blk & 1;
    if (blk + 1 < NBLK) STAGE_LOAD(blk + 1)

    // ---- compute block blk ----
    ldsS[wid][lane] = S;
    asm volatile("s_waitcnt lgkmcnt(0)" ::: "memory");

    float2 vdv[8];
#pragma unroll
    for (int u = 0; u < 8; ++u)
      vdv[u] = *reinterpret_cast<const float2*>(&ldsV[buf][u * 128 + i * 2]);
    const float gv = ldsG[buf][lane];
    float knl[8];
#pragma unroll
    for (int w = 0; w < 8; ++w) knl[w] = ldsT[buf][lane * TSTR + w];

    // MFMA reductions: 2 x mfma_16x16x32, C[r][c] = r_c for all r
    f32x4 red = (f32x4){0.f, 0.f, 0.f, 0.f};
#pragma unroll
    for (int kk = 0; kk < 2; ++kk) {
      float a[8], bsrc[8];
      *reinterpret_cast<float4*>(&a[0]) = *reinterpret_cast<const float4*>(
          &ldsS[wid][kk * 32 + koff]);
      *reinterpret_cast<float4*>(&a[4]) = *reinterpret_cast<const float4*>(
          &ldsS[wid][kk * 32 + koff + 4]);
#pragma unroll
      for (int t = 0; t < 8; ++t)
        bsrc[t] = ldsT[buf][(kk * 32 + koff + t) * TSTR + col];
      union { unsigned u[4]; bf16x8 v; } cvA, cvB;
#pragma unroll
      for (int h = 0; h < 4; ++h) {
        asm("v_cvt_pk_bf16_f32 %0, %1, %2"
            : "=v"(cvA.u[h]) : "v"(a[2 * h]), "v"(a[2 * h + 1]));
        asm("v_cvt_pk_bf16_f32 %0, %1, %2"
            : "=v"(cvB.u[h]) : "v"(bsrc[2 * h]), "v"(bsrc[2 * h + 1]));
      }
      red = __builtin_amdgcn_mfma_f32_16x16x32_bf16(cvA.v, cvB.v, red, 0, 0, 0);
    }

    // prefix products + reciprocals (overlaps MFMA latency)
    float c[9], rc[8];
    c[0] = 1.f;
#pragma unroll
    for (int u = 0; u < 8; ++u) {
      c[u + 1] = c[u] * vdv[u].y;
      rc[u] = __builtin_amdgcn_rcpf(c[u + 1]);
    }

    // broadcast the 16 reductions (lane u holds r_u in red[0])
    float acc[8], sac[8];
    const int ri = __float_as_int(red[0]);
#pragma unroll
    for (int u = 0; u < 8; ++u) {
      acc[u] = __int_as_float(__builtin_amdgcn_readlane(ri, u));
      sac[u] = __int_as_float(__builtin_amdgcn_readlane(ri, 8 + u));
    }

    // factored UT-transform recurrence (verified R6)
    float dp[8], sqv[8];
#pragma unroll
    for (int w = 0; w < 8; ++w) {
      const float d = fmaf(-c[w], acc[w], vdv[w].x);
      dp[w] = d * rc[w];
      sqv[w] = fmaf(c[w + 1], sac[w], d * GM(w * 8 + w));
#pragma unroll
      for (int u = w + 1; u < 8; ++u) {
        acc[u] = fmaf(dp[w], GM(w * 8 + u), acc[u]);   // G[w][u]
        sac[u] = fmaf(dp[w], GM(u * 8 + w), sac[u]);   // H[u][w]
      }
    }
    float tacc = S;
#pragma unroll
    for (int w = 0; w < 8; ++w) tacc = fmaf(dp[w], knl[w], tacc);
    S = c[8] * tacc;

    // fused silu output: sqv[] is wave-uniform -> lane u selects sqv[u]
    if (lane < 8) {
      const float a0 = (lane & 1) ? sqv[1] : sqv[0];
      const float a1 = (lane & 1) ? sqv[3] : sqv[2];
      const float a2 = (lane & 1) ? sqv[5] : sqv[4];
      const float a3 = (lane & 1) ? sqv[7] : sqv[6];
      const float b0 = (lane & 2) ? a1 : a0;
      const float b1 = (lane & 2) ? a3 : a2;
      const float sq = (lane & 4) ? b1 : b0;
      const size_t ob = (size_t)blk * U_BLK * (B_SZ * N_SZ) + b * N_SZ + i;
      out[ob + (size_t)lane * (B_SZ * N_SZ)] =
          sq * sq * __fdividef(1.f, 1.f + __expf(-sq));
    }
    // ---- end compute ----

    if (blk + 1 < NBLK) STAGE_WRITE(buf ^ 1)
    __syncthreads();
  }

  Sfin[(size_t)b * 4096 + i * 64 + lane] = S;
#undef STAGE_LOAD
#undef STAGE_WRITE
#undef GM
}

// ---------------------------------------------------------------------------
extern "C" void kernel_launch(void* const* d_in, const int* in_sizes, int n_in,
                              void* d_out, int out_size, void* d_ws, size_t ws_size,
                              hipStream_t stream) {
  const float* x      = (const float*)d_in[0];
  const float* S0     = (const float*)d_in[1];
  const float* W      = (const float*)d_in[2];
  const float* b_gate = (const float*)d_in[3];
  float* out  = (float*)d_out;
  float* proj = (float*)d_ws;                                        // 33.55 MB
  float* gram = (float*)((char*)d_ws + (size_t)M_ROWS * NOUT * 4);   // +1 MB
  unsigned* Wb = (unsigned*)((char*)d_ws + 35u * 1024 * 1024);       // +0.5 MB

  hipLaunchKernelGGL(wcvt, dim3(256), dim3(256), 0, stream, W, Wb);
  hipLaunchKernelGGL(gemm_proj, dim3(M_ROWS / 64), dim3(256), 0, stream,
                     x, (const unsigned short*)Wb, proj, b_gate);
  hipLaunchKernelGGL(gram_kernel, dim3(32768 / 4), dim3(256), 0, stream,
                     proj, gram);
  hipLaunchKernelGGL(scan_kernel, dim3(256), dim3(256), 0, stream,
                     proj, gram, S0, out, out + (size_t)T_STEPS * B_SZ * N_SZ);
}

// Round 23
// 324.139 us; speedup vs baseline: 1.1058x; 1.1058x over previous
//
#include <hip/hip_runtime.h>
#include <hip/hip_bf16.h>
#include <math.h>

#define T_STEPS 2048
#define B_SZ 16
#define D_SZ 1024
#define N_SZ 64
#define M_ROWS (T_STEPS * B_SZ)   // 32768
#define NOUT (4 * N_SZ)           // 256
#define U_BLK 8
#define NBLK (T_STEPS / U_BLK)    // 256
#define TSTR 17                   // transposed kn/q LDS row stride (floats)

typedef __attribute__((ext_vector_type(8))) short bf16x8;
typedef __attribute__((ext_vector_type(4))) float f32x4;

// ---------------------------------------------------------------------------
// DPP reduction (R4-R6 verified) — used by norm_gram only.
// ---------------------------------------------------------------------------
template <int CTRL, int RMASK, bool BC>
__device__ __forceinline__ float dpp_add(float v) {
  return v + __int_as_float(__builtin_amdgcn_update_dpp(
                 0, __float_as_int(v), CTRL, RMASK, 0xF, BC));
}
__device__ __forceinline__ float wave_red(float v) {
  v = dpp_add<0xB1, 0xF, true>(v);
  v = dpp_add<0x4E, 0xF, true>(v);
  v = dpp_add<0x141, 0xF, true>(v);
  v = dpp_add<0x140, 0xF, true>(v);
  v = dpp_add<0x142, 0xA, false>(v);
  v = dpp_add<0x143, 0xC, false>(v);
  return __int_as_float(__builtin_amdgcn_readlane(__float_as_int(v), 63));
}

// fp32 pair -> packed bf16x2 (RNE) via v_cvt_pk_bf16_f32.
__device__ __forceinline__ unsigned cvt2(float a, float b) {
  float2 f; f.x = a; f.y = b;
  __hip_bfloat162 h = __float22bfloat162_rn(f);
  return *reinterpret_cast<unsigned*>(&h);
}

// ---------------------------------------------------------------------------
// Kernel 0: W (fp32, 1 MB) -> Wb (bf16, 0.5 MB), once (R20-verified).
// ---------------------------------------------------------------------------
__global__ __launch_bounds__(256) void wcvt(const float* __restrict__ W,
                                            unsigned* __restrict__ Wb) {
  const size_t idx = ((size_t)blockIdx.x * 256 + threadIdx.x) * 4;
  const float4 f = *reinterpret_cast<const float4*>(&W[idx]);
  uint2 o;
  o.x = cvt2(f.x, f.y);
  o.y = cvt2(f.z, f.w);
  *reinterpret_cast<uint2*>(&Wb[idx >> 1]) = o;
}

// ---------------------------------------------------------------------------
// Kernel 1: proj = x @ W^T via bf16 MFMA, bf16 W, plain epilogue
// (R20-verified best GEMM).
// ---------------------------------------------------------------------------
__global__ __launch_bounds__(256) void gemm_proj(const float* __restrict__ x,
                                                 const unsigned short* __restrict__ Wb,
                                                 float* __restrict__ proj) {
  __shared__ unsigned short Al[64][72];
  __shared__ unsigned short Bl[256][72];
  const int tid = threadIdx.x;
  const int lane = tid & 63;
  const int wv = tid >> 6;
  const int m0 = blockIdx.x * 64;
  const int nw0 = wv * 64;

  f32x4 acc[4][4];
#pragma unroll
  for (int m = 0; m < 4; ++m)
#pragma unroll
    for (int n = 0; n < 4; ++n) acc[m][n] = (f32x4){0.f, 0.f, 0.f, 0.f};

  const int arow = tid >> 2;
  const int akb = (tid & 3) * 16;

  for (int k0 = 0; k0 < D_SZ; k0 += 64) {
    {
      const float* src = &x[(size_t)(m0 + arow) * D_SZ + k0 + akb];
      unsigned tmp[8];
#pragma unroll
      for (int c = 0; c < 4; ++c) {
        const float4 f = *reinterpret_cast<const float4*>(src + c * 4);
        tmp[2 * c] = cvt2(f.x, f.y);
        tmp[2 * c + 1] = cvt2(f.z, f.w);
      }
      *reinterpret_cast<float4*>(&Al[arow][akb]) =
          *reinterpret_cast<const float4*>(&tmp[0]);
      *reinterpret_cast<float4*>(&Al[arow][akb + 8]) =
          *reinterpret_cast<const float4*>(&tmp[4]);
    }
    {
      const unsigned short* src = &Wb[(size_t)tid * D_SZ + k0];
#pragma unroll
      for (int h = 0; h < 8; ++h)
        *reinterpret_cast<float4*>(&Bl[tid][h * 8]) =
            *reinterpret_cast<const float4*>(&src[h * 8]);
    }
    __syncthreads();
    const int fr = lane & 15;
#pragma unroll
    for (int kk = 0; kk < 64; kk += 32) {
      const int kof = kk + (lane >> 4) * 8;
      bf16x8 af[4], bfr[4];
#pragma unroll
      for (int m = 0; m < 4; ++m)
        af[m] = *reinterpret_cast<const bf16x8*>(&Al[m * 16 + fr][kof]);
#pragma unroll
      for (int n = 0; n < 4; ++n)
        bfr[n] = *reinterpret_cast<const bf16x8*>(&Bl[nw0 + n * 16 + fr][kof]);
#pragma unroll
      for (int m = 0; m < 4; ++m)
#pragma unroll
        for (int n = 0; n < 4; ++n)
          acc[m][n] = __builtin_amdgcn_mfma_f32_16x16x32_bf16(
              af[m], bfr[n], acc[m][n], 0, 0, 0);
    }
    __syncthreads();
  }

  const int col = lane & 15;
  const int rb = (lane >> 4) * 4;
#pragma unroll
  for (int m = 0; m < 4; ++m)
#pragma unroll
    for (int n = 0; n < 4; ++n)
#pragma unroll
      for (int r = 0; r < 4; ++r)
        proj[(size_t)(m0 + m * 16 + rb + r) * NOUT + nw0 + n * 16 + col] =
            acc[m][n][r];
}

// ---------------------------------------------------------------------------
// Kernel 2: FUSED norm+gate+repack+gram (R17-verified, unchanged).
// ---------------------------------------------------------------------------
__global__ __launch_bounds__(512) void norm_gram(float* __restrict__ proj,
                                                 const float* __restrict__ b_gate,
                                                 float* __restrict__ gram) {
  const int u = threadIdx.x >> 6;        // 0..7 : step within block
  const int lane = threadIdx.x & 63;
  const int grp = blockIdx.x;            // b*NBLK + blk
  const int blk = grp & (NBLK - 1);
  const int b = grp >> 8;
  const int t0 = blk * U_BLK;
  const int m = (t0 + u) * B_SZ + b;

  __shared__ float lds_kn[U_BLK][64];    // 2 KB

  float* p = proj + (size_t)m * NOUT;
  const float kf = p[lane];
  const float vf = p[64 + lane];
  const float qf = p[128 + lane];
  const float gf = p[192 + lane];
  const float bg = b_gate[lane];
  const float ss = wave_red(kf * kf);
  const float kn = kf / (sqrtf(ss) + 1e-6f);
  const float dec = 1.f / (1.f + expf(-(gf + bg)));
  asm volatile("s_waitcnt vmcnt(0)" ::: "memory");
  float2* pp = reinterpret_cast<float2*>(p);
  float2 a; a.x = kn; a.y = qf;
  float2 c; c.x = vf; c.y = dec;
  pp[lane] = a;
  pp[64 + lane] = c;

  lds_kn[u][lane] = kn;
  __syncthreads();

  float row[8];
#pragma unroll
  for (int cc = 0; cc < 8; ++cc) {
    const float knc = lds_kn[cc][lane];
    const float lhs = (cc > u) ? kn : qf;
    row[cc] = wave_red(lhs * knc);
  }
  if (lane == 0) {
    float* dst = gram + ((size_t)grp * 64 + u * 8);
    float4 r0, r1;
    r0.x = row[0]; r0.y = row[1]; r0.z = row[2]; r0.w = row[3];
    r1.x = row[4]; r1.y = row[5]; r1.z = row[6]; r1.w = row[7];
    *reinterpret_cast<float4*>(dst) = r0;
    *reinterpret_cast<float4*>(dst + 4) = r1;
  }
}

// ---------------------------------------------------------------------------
// Kernel 3: scan — R18 structure + fused silu output (R22-verified: 271 us).
// ---------------------------------------------------------------------------
__global__ __launch_bounds__(256, 1) void scan_kernel(
    const float* __restrict__ proj, const float* __restrict__ gram,
    const float* __restrict__ S0, float* __restrict__ out,
    float* __restrict__ Sfin) {
  const int wid = threadIdx.x >> 6;     // 0..3
  const int lane = threadIdx.x & 63;
  const int bid = blockIdx.x;
  const int b = (bid & 7) | ((bid >> 7) << 3);     // same XCD for same b
  const int i = (((bid >> 3) & 15) << 2) | wid;

  __shared__ float ldsT[2][64 * TSTR];   // transposed kn/q: [j][u | 8+u]
  __shared__ float ldsV[2][U_BLK * 128]; // row-major (v,dec) pairs
  __shared__ float ldsG[2][64];          // gram row
  __shared__ float ldsS[4][64];          // per-wave S scratch

  float S = S0[(size_t)b * 4096 + i * 64 + lane];

  const int r0 = wid * 2;           // this wave stages rows r0, r0+1
  float4 st0, st1;
  float stg = 0.f;

#define STAGE_LOAD(blkv)                                                      \
  {                                                                           \
    const size_t g0 = ((size_t)(((blkv) * U_BLK + r0) * B_SZ + b)) * NOUT;    \
    st0 = *reinterpret_cast<const float4*>(&proj[g0 + lane * 4]);             \
    st1 = *reinterpret_cast<const float4*>(&proj[g0 + (size_t)B_SZ * NOUT +   \
                                                 lane * 4]);                  \
    if (wid == 0) stg = gram[((size_t)b * NBLK + (blkv)) * 64 + lane];        \
  }

#define STAGE_WRITE(bufv)                                                     \
  {                                                                           \
    if (lane < 32) {                                                          \
      const int j0 = lane * 2;                                                \
      ldsT[bufv][j0 * TSTR + r0] = st0.x;                                     \
      ldsT[bufv][j0 * TSTR + 8 + r0] = st0.y;                                 \
      ldsT[bufv][(j0 + 1) * TSTR + r0] = st0.z;                               \
      ldsT[bufv][(j0 + 1) * TSTR + 8 + r0] = st0.w;                           \
      ldsT[bufv][j0 * TSTR + r0 + 1] = st1.x;                                 \
      ldsT[bufv][j0 * TSTR + 8 + r0 + 1] = st1.y;                             \
      ldsT[bufv][(j0 + 1) * TSTR + r0 + 1] = st1.z;                           \
      ldsT[bufv][(j0 + 1) * TSTR + 8 + r0 + 1] = st1.w;                       \
    } else {                                                                  \
      *reinterpret_cast<float4*>(                                             \
          &ldsV[bufv][r0 * 128 + (lane - 32) * 4]) = st0;                     \
      *reinterpret_cast<float4*>(                                             \
          &ldsV[bufv][(r0 + 1) * 128 + (lane - 32) * 4]) = st1;               \
    }                                                                         \
    if (wid == 0) ldsG[bufv][lane] = stg;                                     \
  }

#define GM(idx) __int_as_float(                                               \
    __builtin_amdgcn_readlane(__float_as_int(gv), (idx)))

  STAGE_LOAD(0)
  STAGE_WRITE(0)
  __syncthreads();

  const int koff = (lane >> 4) * 8;
  const int col = lane & 15;

  for (int blk = 0; blk < NBLK; ++blk) {
    const int buf = blk & 1;
    if (blk + 1 < NBLK) STAGE_LOAD(blk + 1)

    // ---- compute block blk ----
    ldsS[wid][lane] = S;
    asm volatile("s_waitcnt lgkmcnt(0)" ::: "memory");

    float2 vdv[8];
#pragma unroll
    for (int u = 0; u < 8; ++u)
      vdv[u] = *reinterpret_cast<const float2*>(&ldsV[buf][u * 128 + i * 2]);
    const float gv = ldsG[buf][lane];
    float knl[8];
#pragma unroll
    for (int w = 0; w < 8; ++w) knl[w] = ldsT[buf][lane * TSTR + w];

    // MFMA reductions: 2 x mfma_16x16x32, C[r][c] = r_c for all r
    f32x4 red = (f32x4){0.f, 0.f, 0.f, 0.f};
#pragma unroll
    for (int kk = 0; kk < 2; ++kk) {
      float a[8], bsrc[8];
      *reinterpret_cast<float4*>(&a[0]) = *reinterpret_cast<const float4*>(
          &ldsS[wid][kk * 32 + koff]);
      *reinterpret_cast<float4*>(&a[4]) = *reinterpret_cast<const float4*>(
          &ldsS[wid][kk * 32 + koff + 4]);
#pragma unroll
      for (int t = 0; t < 8; ++t)
        bsrc[t] = ldsT[buf][(kk * 32 + koff + t) * TSTR + col];
      union { unsigned u[4]; bf16x8 v; } cvA, cvB;
#pragma unroll
      for (int h = 0; h < 4; ++h) {
        asm("v_cvt_pk_bf16_f32 %0, %1, %2"
            : "=v"(cvA.u[h]) : "v"(a[2 * h]), "v"(a[2 * h + 1]));
        asm("v_cvt_pk_bf16_f32 %0, %1, %2"
            : "=v"(cvB.u[h]) : "v"(bsrc[2 * h]), "v"(bsrc[2 * h + 1]));
      }
      red = __builtin_amdgcn_mfma_f32_16x16x32_bf16(cvA.v, cvB.v, red, 0, 0, 0);
    }

    // prefix products + reciprocals (overlaps MFMA latency)
    float c[9], rc[8];
    c[0] = 1.f;
#pragma unroll
    for (int u = 0; u < 8; ++u) {
      c[u + 1] = c[u] * vdv[u].y;
      rc[u] = __builtin_amdgcn_rcpf(c[u + 1]);
    }

    // broadcast the 16 reductions (lane u holds r_u in red[0])
    float acc[8], sac[8];
    const int ri = __float_as_int(red[0]);
#pragma unroll
    for (int u = 0; u < 8; ++u) {
      acc[u] = __int_as_float(__builtin_amdgcn_readlane(ri, u));
      sac[u] = __int_as_float(__builtin_amdgcn_readlane(ri, 8 + u));
    }

    // factored UT-transform recurrence (verified R6)
    float dp[8], sqv[8];
#pragma unroll
    for (int w = 0; w < 8; ++w) {
      const float d = fmaf(-c[w], acc[w], vdv[w].x);
      dp[w] = d * rc[w];
      sqv[w] = fmaf(c[w + 1], sac[w], d * GM(w * 8 + w));
#pragma unroll
      for (int u = w + 1; u < 8; ++u) {
        acc[u] = fmaf(dp[w], GM(w * 8 + u), acc[u]);   // G[w][u]
        sac[u] = fmaf(dp[w], GM(u * 8 + w), sac[u]);   // H[u][w]
      }
    }
    float tacc = S;
#pragma unroll
    for (int w = 0; w < 8; ++w) tacc = fmaf(dp[w], knl[w], tacc);
    S = c[8] * tacc;

    // fused silu output: sqv[] is wave-uniform -> lane u selects sqv[u]
    if (lane < 8) {
      const float a0 = (lane & 1) ? sqv[1] : sqv[0];
      const float a1 = (lane & 1) ? sqv[3] : sqv[2];
      const float a2 = (lane & 1) ? sqv[5] : sqv[4];
      const float a3 = (lane & 1) ? sqv[7] : sqv[6];
      const float b0 = (lane & 2) ? a1 : a0;
      const float b1 = (lane & 2) ? a3 : a2;
      const float sq = (lane & 4) ? b1 : b0;
      const size_t ob = (size_t)blk * U_BLK * (B_SZ * N_SZ) + b * N_SZ + i;
      out[ob + (size_t)lane * (B_SZ * N_SZ)] =
          sq * sq * __fdividef(1.f, 1.f + __expf(-sq));
    }
    // ---- end compute ----

    if (blk + 1 < NBLK) STAGE_WRITE(buf ^ 1)
    __syncthreads();
  }

  Sfin[(size_t)b * 4096 + i * 64 + lane] = S;
#undef STAGE_LOAD
#undef STAGE_WRITE
#undef GM
}

// ---------------------------------------------------------------------------
extern "C" void kernel_launch(void* const* d_in, const int* in_sizes, int n_in,
                              void* d_out, int out_size, void* d_ws, size_t ws_size,
                              hipStream_t stream) {
  const float* x      = (const float*)d_in[0];
  const float* S0     = (const float*)d_in[1];
  const float* W      = (const float*)d_in[2];
  const float* b_gate = (const float*)d_in[3];
  float* out  = (float*)d_out;
  float* proj = (float*)d_ws;                                        // 33.55 MB
  float* gram = (float*)((char*)d_ws + (size_t)M_ROWS * NOUT * 4);   // +1 MB
  unsigned* Wb = (unsigned*)((char*)d_ws + 35u * 1024 * 1024);       // +0.5 MB

  hipLaunchKernelGGL(wcvt, dim3(256), dim3(256), 0, stream, W, Wb);
  hipLaunchKernelGGL(gemm_proj, dim3(M_ROWS / 64), dim3(256), 0, stream,
                     x, (const unsigned short*)Wb, proj);
  hipLaunchKernelGGL(norm_gram, dim3(B_SZ * NBLK), dim3(512), 0, stream,
                     proj, b_gate, gram);
  hipLaunchKernelGGL(scan_kernel, dim3(256), dim3(256), 0, stream,
                     proj, gram, S0, out, out + (size_t)T_STEPS * B_SZ * N_SZ);
}